// Round 2
// baseline (110.528 us; speedup 1.0000x reference)
//
#include <hip/hip_runtime.h>
#include <math.h>

// Problem constants (from reference)
#define D 1024      // INPUT_SIZE
#define M 4096      // OUT_H * OUT_W
#define B 64        // BATCH
#define SOM_EPS 1e-6

// Single fused kernel. Algebra:
//   dist2[b,d] = sum_m (s - w[d,m])^2 = M*s^2 - 2*s*S1[d] + S2[d],  s = x[b,d]+eps
// Phase 1 (all 1024 blocks): block d computes S1[d], S2[d] in double from the
//   contiguous 16 KB weight row (float4 coalesced), publishes via release-store
//   flag1[d]=1. Flags live in d_ws, which the harness poisons to 0xAA ->
//   initial value 0xAAAAAAAA != 1, so no init kernel is needed. If poison is
//   skipped between replays the re-computed values are bitwise identical, so
//   early readers are still correct (idempotent handshake).
// Phase 2 (blocks 0..63): spin on all flags (agent-scope acquire), then per
//   batch b compute the double-precision argmin over d (exact-math ordering ->
//   matches the np reference's argmin; ties effectively impossible), write the
//   two location floats and loss[b], publish flag2[b].
// Phase 3 (block 0): wait on flag2[0..63], write out[128] = sum(sqrt)/B.
// Deadlock-free without cooperative launch: 1024 blocks x 256 threads at low
// VGPR all fit co-resident (256 CU x 2048 thr), and only 64 blocks spin.
__global__ __launch_bounds__(256) void som_fused(const float* __restrict__ x,
                                                 const float* __restrict__ w,
                                                 const float* __restrict__ loc,
                                                 float* __restrict__ out,
                                                 double* __restrict__ S1,
                                                 double* __restrict__ S2,
                                                 double* __restrict__ lossv,
                                                 unsigned* __restrict__ flag1,
                                                 unsigned* __restrict__ flag2) {
    const int d    = blockIdx.x;
    const int t    = threadIdx.x;
    const int wave = t >> 6, lane = t & 63;

    // ---------------- phase 1: moments of weight row d ----------------
    const float4* row = (const float4*)(w + (size_t)d * M);
    double a1 = 0.0, a2 = 0.0;
#pragma unroll
    for (int k = 0; k < 4; ++k) {               // 4 * 256 float4 = 4096 floats
        float4 v = row[t + k * 256];
        double vx = v.x, vy = v.y, vz = v.z, vw = v.w;
        a1 += vx + vy + vz + vw;
        a2 += vx * vx + vy * vy + vz * vz + vw * vw;
    }
    for (int off = 32; off > 0; off >>= 1) {
        a1 += __shfl_down(a1, off);
        a2 += __shfl_down(a2, off);
    }
    __shared__ double l1[4], l2[4];
    if (lane == 0) { l1[wave] = a1; l2[wave] = a2; }
    __syncthreads();
    if (t == 0) {
        S1[d] = l1[0] + l1[1] + l1[2] + l1[3];
        S2[d] = l2[0] + l2[1] + l2[2] + l2[3];
        __threadfence();  // S1/S2 visible device-wide before the flag
        __hip_atomic_store(&flag1[d], 1u, __ATOMIC_RELEASE, __HIP_MEMORY_SCOPE_AGENT);
    }

    if (blockIdx.x >= B) return;  // blocks 64..1023 are phase-1 only
    const int b = blockIdx.x;

    // ---------------- wait for all 1024 rows ----------------
#pragma unroll
    for (int k = 0; k < 4; ++k) {
        const unsigned* f = &flag1[t + k * 256];
        while (__hip_atomic_load(f, __ATOMIC_ACQUIRE, __HIP_MEMORY_SCOPE_AGENT) != 1u) { }
    }
    __syncthreads();

    // ---------------- phase 2: per-batch argmin over d ----------------
    double bv = 1e300;
    int    bi = 0;
#pragma unroll
    for (int k = 0; k < 4; ++k) {               // dd ascending per thread
        int dd = t + k * 256;
        double s = (double)x[b * D + dd] + SOM_EPS;   // coalesced
        double v = (double)M * s * s - 2.0 * s * S1[dd] + S2[dd];
        if (v < bv) { bv = v; bi = dd; }        // strict < keeps first index
    }
    for (int off = 32; off > 0; off >>= 1) {
        double ov = __shfl_down(bv, off);
        int    oi = __shfl_down(bi, off);
        if (ov < bv || (ov == bv && oi < bi)) { bv = ov; bi = oi; }
    }
    __shared__ double sv[4];
    __shared__ int    si[4];
    if (lane == 0) { sv[wave] = bv; si[wave] = bi; }
    __syncthreads();
    if (t == 0) {
        for (int wv2 = 1; wv2 < 4; ++wv2)
            if (sv[wv2] < bv || (sv[wv2] == bv && si[wv2] < bi)) { bv = sv[wv2]; bi = si[wv2]; }
        out[2 * b]     = loc[2 * bi];
        out[2 * b + 1] = loc[2 * bi + 1];
        lossv[b] = sqrt(bv);
        __threadfence();
        __hip_atomic_store(&flag2[b], 1u, __ATOMIC_RELEASE, __HIP_MEMORY_SCOPE_AGENT);
    }

    // ---------------- phase 3: block 0 sums the 64 losses ----------------
    if (b == 0) {
        if (t < B) {
            while (__hip_atomic_load(&flag2[t], __ATOMIC_ACQUIRE, __HIP_MEMORY_SCOPE_AGENT) != 1u) { }
        }
        __syncthreads();
        if (t == 0) {
            double sum = 0.0;
            for (int i = 0; i < B; ++i) sum += lossv[i];
            out[2 * B] = (float)(sum / (double)B);
        }
    }
}

extern "C" void kernel_launch(void* const* d_in, const int* in_sizes, int n_in,
                              void* d_out, int out_size, void* d_ws, size_t ws_size,
                              hipStream_t stream) {
    const float* x   = (const float*)d_in[0];   // [B, D]
    const float* w   = (const float*)d_in[1];   // [D, M]
    const float* loc = (const float*)d_in[2];   // [M, 2]
    float* out = (float*)d_out;                 // [2*B locations, then loss]

    // ws layout: S1[D], S2[D], lossv[B] doubles; then flag1[D], flag2[B] u32
    double*   ws_d  = (double*)d_ws;
    double*   S1    = ws_d;
    double*   S2    = ws_d + D;
    double*   lossv = ws_d + 2 * D;
    unsigned* flag1 = (unsigned*)(ws_d + 2 * D + B);
    unsigned* flag2 = flag1 + D;

    som_fused<<<D, 256, 0, stream>>>(x, w, loc, out, S1, S2, lossv, flag1, flag2);
}

// Round 3
// 76.068 us; speedup vs baseline: 1.4530x; 1.4530x over previous
//
#include <hip/hip_runtime.h>
#include <math.h>

// Problem constants (from reference)
#define D 1024      // INPUT_SIZE
#define M 4096      // OUT_H * OUT_W
#define B 64        // BATCH
#define SOM_EPS 1e-6

// Two kernels; the kernel boundary is the producer->consumer barrier (the
// command processor's end-of-kernel cache maintenance makes K1's stores
// visible to K2 on all XCDs -- R2 showed an in-kernel flag barrier costs
// ~50 us in threadfence/acquire traffic, vs ~free here).
//
// Algebra: dist2[b,d] = sum_m (s - w[d,m])^2 = M*s^2 - 2*s*S1[d] + S2[d],
// s = x[b,d] + eps. All moment/argmin math in double so the argmin ordering
// matches the exact-math (np reference) argmin bit-for-bit.

// ---------------------------------------------------------------------------
// K1: per-row moments of weight [D, M]; block d -> S1[d], S2[d].
// Also zeroes the loss accumulator + done counter (ws is poisoned to 0xAA
// before every timed launch; stream order publishes the zeros to K2).
// ---------------------------------------------------------------------------
__global__ __launch_bounds__(256) void som_stats(const float* __restrict__ w,
                                                 double* __restrict__ S1,
                                                 double* __restrict__ S2,
                                                 double* __restrict__ acc,
                                                 unsigned* __restrict__ counter) {
    const int d = blockIdx.x;
    const int t = threadIdx.x;
    const float4* row = (const float4*)(w + (size_t)d * M);

    double a1 = 0.0, a2 = 0.0;
#pragma unroll
    for (int k = 0; k < 4; ++k) {               // 4 * 256 float4 = 4096 floats
        float4 v = row[t + k * 256];
        double vx = v.x, vy = v.y, vz = v.z, vw = v.w;
        a1 += vx + vy + vz + vw;
        a2 += vx * vx + vy * vy + vz * vz + vw * vw;
    }
    for (int off = 32; off > 0; off >>= 1) {
        a1 += __shfl_down(a1, off);
        a2 += __shfl_down(a2, off);
    }
    __shared__ double l1[4], l2[4];
    const int wave = t >> 6, lane = t & 63;
    if (lane == 0) { l1[wave] = a1; l2[wave] = a2; }
    __syncthreads();
    if (t == 0) {
        S1[d] = l1[0] + l1[1] + l1[2] + l1[3];
        S2[d] = l2[0] + l2[1] + l2[2] + l2[3];
        if (d == 0) { *acc = 0.0; *counter = 0u; }   // un-poison reduction state
    }
}

// ---------------------------------------------------------------------------
// K2: block b computes the double-precision argmin over d, writes the two
// location floats, atomically accumulates sqrt(min) into acc, and the last
// block to finish writes out[2B] = acc / B.
// ---------------------------------------------------------------------------
__global__ __launch_bounds__(1024) void som_argmin_loss(const float* __restrict__ x,
                                                        const double* __restrict__ S1,
                                                        const double* __restrict__ S2,
                                                        const float* __restrict__ loc,
                                                        float* __restrict__ out,
                                                        double* __restrict__ acc,
                                                        unsigned* __restrict__ counter) {
    const int b = blockIdx.x;
    const int t = threadIdx.x;

    double s = (double)x[b * D + t] + SOM_EPS;
    double bv = (double)M * s * s - 2.0 * s * S1[t] + S2[t];
    int bi = t;

    // wave (64-lane) argmin; tie-break keeps lower index (first occurrence)
    for (int off = 32; off > 0; off >>= 1) {
        double ov = __shfl_down(bv, off);
        int    oi = __shfl_down(bi, off);
        if (ov < bv || (ov == bv && oi < bi)) { bv = ov; bi = oi; }
    }
    __shared__ double sv[16];
    __shared__ int    si[16];
    const int wave = t >> 6, lane = t & 63;
    if (lane == 0) { sv[wave] = bv; si[wave] = bi; }
    __syncthreads();

    if (t == 0) {
        for (int wv = 1; wv < 16; ++wv)
            if (sv[wv] < bv || (sv[wv] == bv && si[wv] < bi)) { bv = sv[wv]; bi = si[wv]; }
        out[2 * b]     = loc[2 * bi];
        out[2 * b + 1] = loc[2 * bi + 1];

        atomicAdd(acc, sqrt(bv));   // device-scope
        // acq_rel: waits for the acc add to complete before the increment is
        // visible; the winner's acquire sees every block's contribution.
        unsigned old = __hip_atomic_fetch_add(counter, 1u, __ATOMIC_ACQ_REL,
                                              __HIP_MEMORY_SCOPE_AGENT);
        if (old == B - 1) {
            double total = __hip_atomic_load(acc, __ATOMIC_ACQUIRE,
                                             __HIP_MEMORY_SCOPE_AGENT);
            out[2 * B] = (float)(total / (double)B);
        }
    }
}

extern "C" void kernel_launch(void* const* d_in, const int* in_sizes, int n_in,
                              void* d_out, int out_size, void* d_ws, size_t ws_size,
                              hipStream_t stream) {
    const float* x   = (const float*)d_in[0];   // [B, D]
    const float* w   = (const float*)d_in[1];   // [D, M]
    const float* loc = (const float*)d_in[2];   // [M, 2]
    float* out = (float*)d_out;                 // [2*B locations, then loss]

    // ws layout (doubles): S1[D], S2[D], acc; then counter (u32)
    double*   ws_d    = (double*)d_ws;
    double*   S1      = ws_d;
    double*   S2      = ws_d + D;
    double*   acc     = ws_d + 2 * D;
    unsigned* counter = (unsigned*)(ws_d + 2 * D + 1);

    som_stats      <<<D, 256, 0, stream>>>(w, S1, S2, acc, counter);
    som_argmin_loss<<<B, 1024, 0, stream>>>(x, S1, S2, loc, out, acc, counter);
}